// Round 3
// baseline (170.737 us; speedup 1.0000x reference)
//
#include <hip/hip_runtime.h>
#include <hip/hip_bf16.h>
#include <stdint.h>
#include <stddef.h>

typedef __bf16 bf16x8 __attribute__((ext_vector_type(8)));
typedef __bf16 bf16x4 __attribute__((ext_vector_type(4)));
typedef float  f32x4  __attribute__((ext_vector_type(4)));

#define PAIR_BLOCKS 2048
#define CAST_BLOCKS 2048
#define TR_BLOCKS   256

// ---------------- fused prep: pair_bias (MFMA, split-float) + tokens cast + weight transposes ----
// pair bias: pb[h][nm] = sum_p pf[nm][p] * Wp[p][h]; rows = flat (n,m), done as
// [512 rows x 64] x [64 x 8] GEMM per block via mfma_f32_16x16x32_bf16 with hi/lo split.
__global__ __launch_bounds__(256) void prep_kernel(
    const float* __restrict__ tokens, const float* __restrict__ pf,
    const float* __restrict__ Wq, const float* __restrict__ Wk,
    const float* __restrict__ Wv, const float* __restrict__ Wo,
    const float* __restrict__ Wp,
    __bf16* __restrict__ tok_bf, __bf16* __restrict__ WcatT,
    __bf16* __restrict__ WoT, __bf16* __restrict__ pbb) {
  __shared__ float ls[64][65];
  int bx = blockIdx.x, tid = threadIdx.x;
  if (bx < PAIR_BLOCKS) {
    int wave = tid >> 6, lane = tid & 63;
    int lg = lane >> 4, lr = lane & 15;
    // B fragments of Wp (16x16 cols, only cols 0..7 used), split hi/lo
    bf16x8 whi[2], wlo[2];
#pragma unroll
    for (int s = 0; s < 2; ++s)
#pragma unroll
      for (int j = 0; j < 8; ++j) {
        int p = s * 32 + lg * 8 + j;
        float w = (lr < 8) ? Wp[p * 8 + lr] : 0.f;
        __bf16 h = (__bf16)w;
        whi[s][j] = h;
        wlo[s][j] = (__bf16)(w - (float)h);
      }
    int wbase = bx * 512 + wave * 128;
#pragma unroll 2
    for (int t = 0; t < 8; ++t) {
      int rowt = wbase + t * 16;
      const float* rp = pf + (size_t)(rowt + lr) * 64;
      f32x4 raw[2][2];
#pragma unroll
      for (int s = 0; s < 2; ++s) {
        raw[s][0] = *(const f32x4*)&rp[s * 32 + lg * 8];
        raw[s][1] = *(const f32x4*)&rp[s * 32 + lg * 8 + 4];
      }
      bf16x8 ahi[2], alo[2];
#pragma unroll
      for (int s = 0; s < 2; ++s)
#pragma unroll
        for (int j = 0; j < 8; ++j) {
          float x = raw[s][j >> 2][j & 3];
          __bf16 h = (__bf16)x;
          ahi[s][j] = h;
          alo[s][j] = (__bf16)(x - (float)h);
        }
      f32x4 acc = {0.f, 0.f, 0.f, 0.f};
#pragma unroll
      for (int s = 0; s < 2; ++s) {
        acc = __builtin_amdgcn_mfma_f32_16x16x32_bf16(ahi[s], whi[s], acc, 0, 0, 0);
        acc = __builtin_amdgcn_mfma_f32_16x16x32_bf16(ahi[s], wlo[s], acc, 0, 0, 0);
        acc = __builtin_amdgcn_mfma_f32_16x16x32_bf16(alo[s], whi[s], acc, 0, 0, 0);
      }
      if (lr < 8) {   // D: col=lr=h, row=lg*4+r
        bf16x4 pk;
#pragma unroll
        for (int r = 0; r < 4; ++r) pk[r] = (__bf16)acc[r];
        *(bf16x4*)&pbb[((size_t)lr << 20) + rowt + lg * 4] = pk;
      }
    }
  } else if (bx < PAIR_BLOCKS + CAST_BLOCKS) {
    int i = (bx - PAIR_BLOCKS) * 256 + tid;
    float4 f = ((const float4*)tokens)[i];
    bf16x4 v;
    v[0] = (__bf16)f.x; v[1] = (__bf16)f.y; v[2] = (__bf16)f.z; v[3] = (__bf16)f.w;
    ((bf16x4*)tok_bf)[i] = v;
  } else {
    int t = bx - (PAIR_BLOCKS + CAST_BLOCKS);
    int which = t >> 6; t &= 63;
    const float* in = which == 0 ? Wq : which == 1 ? Wk : which == 2 ? Wv : Wo;
    __bf16* out = which < 3 ? (WcatT + (size_t)which * 512 * 512) : WoT;
    int tc = (t & 7) * 64, tr = (t >> 3) * 64;
#pragma unroll
    for (int i = 0; i < 16; ++i) {
      int e = tid + i * 256, r = e >> 6, c = e & 63;
      ls[r][c] = in[(size_t)(tr + r) * 512 + tc + c];
    }
    __syncthreads();
#pragma unroll
    for (int i = 0; i < 16; ++i) {
      int e = tid + i * 256, r = e >> 6, c = e & 63;
      out[(size_t)(tc + r) * 512 + tr + c] = (__bf16)ls[c][r];
    }
  }
}

// ---------------- shared 128x128 GEMM mainloop ----------------
__device__ __forceinline__ void gemm_mainloop_128(const __bf16* __restrict__ A,
                                                  const __bf16* __restrict__ Bt,
                                                  int K, int m0, int n0,
                                                  f32x4 (&acc)[4][4]) {
  __shared__ __bf16 As[128][40];
  __shared__ __bf16 Bs[128][40];
  int tid = threadIdx.x;
  int wave = tid >> 6, lane = tid & 63;
  int wm = (wave >> 1) * 64, wn = (wave & 1) * 64;
  int lg = lane >> 4, lr = lane & 15;
#pragma unroll
  for (int i = 0; i < 4; ++i)
#pragma unroll
    for (int j = 0; j < 4; ++j) acc[i][j] = (f32x4){0.f, 0.f, 0.f, 0.f};

  for (int k0 = 0; k0 < K; k0 += 32) {
    __syncthreads();
#pragma unroll
    for (int i = 0; i < 2; ++i) {
      int cid = tid + i * 256;
      int row = cid >> 2, c8 = (cid & 3) * 8;
      *(bf16x8*)&As[row][c8] = *(const bf16x8*)&A[(size_t)(m0 + row) * K + k0 + c8];
      *(bf16x8*)&Bs[row][c8] = *(const bf16x8*)&Bt[(size_t)(n0 + row) * K + k0 + c8];
    }
    __syncthreads();
    bf16x8 af[4], bfr[4];
#pragma unroll
    for (int i = 0; i < 4; ++i) {
      af[i]  = *(const bf16x8*)&As[wm + i * 16 + lr][lg * 8];
      bfr[i] = *(const bf16x8*)&Bs[wn + i * 16 + lr][lg * 8];
    }
#pragma unroll
    for (int i = 0; i < 4; ++i)
#pragma unroll
      for (int j = 0; j < 4; ++j)
        acc[i][j] = __builtin_amdgcn_mfma_f32_16x16x32_bf16(af[i], bfr[j], acc[i][j], 0, 0, 0);
  }
}

// ---------------- fused QKV projection GEMM: [4096,512] x [512,1536] ----------------
__global__ __launch_bounds__(256) void qkv_gemm_kernel(const __bf16* __restrict__ A,
                                                       const __bf16* __restrict__ Bt,
                                                       const float* __restrict__ bq,
                                                       const float* __restrict__ bk,
                                                       const float* __restrict__ bv,
                                                       __bf16* __restrict__ qb,
                                                       __bf16* __restrict__ kb,
                                                       __bf16* __restrict__ vtb) {
  int m0 = blockIdx.y * 128, n0 = blockIdx.x * 128;
  f32x4 acc[4][4];
  gemm_mainloop_128(A, Bt, 512, m0, n0, acc);
  int tid = threadIdx.x, wave = tid >> 6, lane = tid & 63;
  int wm = (wave >> 1) * 64, wn = (wave & 1) * 64, lg = lane >> 4, lr = lane & 15;
#pragma unroll
  for (int i = 0; i < 4; ++i)
#pragma unroll
    for (int j = 0; j < 4; ++j) {
      int grow0 = m0 + wm + i * 16 + lg * 4;
      int gcol = n0 + wn + j * 16 + lr;
      int sel = gcol >> 9, c = gcol & 511;
      int hh = c >> 6, dd = c & 63;
      int b = grow0 >> 10, n = grow0 & 1023;
      if (sel == 2) {
        float bias = bv[c];
        bf16x4 pack;
#pragma unroll
        for (int r = 0; r < 4; ++r) pack[r] = (__bf16)(acc[i][j][r] + bias);
        *(bf16x4*)&vtb[(((size_t)(b * 8 + hh)) * 64 + dd) * 1024 + n] = pack;
      } else {
        float bias = (sel == 0 ? bq : bk)[c];
        __bf16* dst = sel == 0 ? qb : kb;
#pragma unroll
        for (int r = 0; r < 4; ++r)
          dst[(((size_t)(b * 8 + hh)) * 1024 + n + r) * 64 + dd] = (__bf16)(acc[i][j][r] + bias);
      }
    }
}

// ---------------- flash attention v2: S^T = K Q^T, direct-reg bias, wave-private P ----------------
__global__ __launch_bounds__(256) void flash_kernel(const __bf16* __restrict__ qg,
                                                    const __bf16* __restrict__ kg,
                                                    const __bf16* __restrict__ vtg,
                                                    const __bf16* __restrict__ pbg,
                                                    __bf16* __restrict__ merged) {
  __shared__ __bf16 pls[4][16][72];    // per-wave P tile [16 q][64 m] -- wave-private, no barriers
  int bh = blockIdx.y, b = bh >> 3, h = bh & 7;
  int q0 = blockIdx.x * 64;
  int tid = threadIdx.x, wave = tid >> 6, lane = tid & 63;
  int lg = lane >> 4, lr = lane & 15;
  const __bf16* qp = qg + (size_t)bh * 1024 * 64;
  const __bf16* kp = kg + (size_t)bh * 1024 * 64;
  const __bf16* vp = vtg + (size_t)bh * 64 * 1024;
  const __bf16* pbh = pbg + ((size_t)h << 20);

  int qw0 = q0 + wave * 16;
  // Q fragments (second operand): q = qw0 + lr
  bf16x8 qf[2];
#pragma unroll
  for (int c = 0; c < 2; ++c)
    qf[c] = *(const bf16x8*)&qp[(size_t)(qw0 + lr) * 64 + c * 32 + lg * 8];

  float mrow = -1e30f, lrow = 0.f;     // softmax state for q = qw0 + lr
  f32x4 of[4] = {};                    // O: row q_local = lg*4+r, col d = dn*16+lr
  const float scale = 0.125f;

  for (int kb2 = 0; kb2 < 16; ++kb2) {
    // K fragments (first operand): m-row = kb2*64 + n*16 + lr
    bf16x8 kf[4][2];
#pragma unroll
    for (int n = 0; n < 4; ++n)
#pragma unroll
      for (int c = 0; c < 2; ++c)
        kf[n][c] = *(const bf16x8*)&kp[(size_t)(kb2 * 64 + n * 16 + lr) * 64 + c * 32 + lg * 8];

    // bias: element r at (q = qw0+lr, m = kb2*64 + n*16 + lg*4 + r) -> contiguous bf16x4
    bf16x4 bias[4];
#pragma unroll
    for (int n = 0; n < 4; ++n)
      bias[n] = *(const bf16x4*)&pbh[(size_t)(qw0 + lr) * 1024 + kb2 * 64 + n * 16 + lg * 4];

    // S^T tiles: D row = m (lg*4+r), col = q (lr)
    f32x4 sv[4];
#pragma unroll
    for (int n = 0; n < 4; ++n) {
      f32x4 z = {0.f, 0.f, 0.f, 0.f};
      z = __builtin_amdgcn_mfma_f32_16x16x32_bf16(kf[n][0], qf[0], z, 0, 0, 0);
      z = __builtin_amdgcn_mfma_f32_16x16x32_bf16(kf[n][1], qf[1], z, 0, 0, 0);
      sv[n] = z;
    }
#pragma unroll
    for (int n = 0; n < 4; ++n)
#pragma unroll
      for (int r = 0; r < 4; ++r)
        sv[n][r] = sv[n][r] * scale + (float)bias[n][r];

    // online softmax for q = qw0+lr: 16 values in-thread, then reduce across lg (lane bits 4,5)
    float tm = -1e30f;
#pragma unroll
    for (int n = 0; n < 4; ++n)
#pragma unroll
      for (int r = 0; r < 4; ++r) tm = fmaxf(tm, sv[n][r]);
    tm = fmaxf(tm, __shfl_xor(tm, 16));
    tm = fmaxf(tm, __shfl_xor(tm, 32));
    float newm = fmaxf(mrow, tm);
    float fs = __expf(mrow - newm);
    mrow = newm;
    float rs = 0.f;
#pragma unroll
    for (int n = 0; n < 4; ++n)
#pragma unroll
      for (int r = 0; r < 4; ++r) {
        float p = __expf(sv[n][r] - newm);
        sv[n][r] = p;
        rs += p;
      }
    rs += __shfl_xor(rs, 16);
    rs += __shfl_xor(rs, 32);
    lrow = lrow * fs + rs;

    // write P (bf16) into wave-private LDS: pls[wave][q=lr][m = n*16+lg*4 + r]
#pragma unroll
    for (int n = 0; n < 4; ++n) {
      bf16x4 pk;
#pragma unroll
      for (int r = 0; r < 4; ++r) pk[r] = (__bf16)sv[n][r];
      *(bf16x4*)&pls[wave][lr][n * 16 + lg * 4] = pk;
    }

    // rescale O by fs redistributed to q_local = lg*4+r
#pragma unroll
    for (int r = 0; r < 4; ++r) {
      float fsq = __shfl(fs, (lane & 48) | (lg * 4 + r));
#pragma unroll
      for (int dn = 0; dn < 4; ++dn) of[dn][r] *= fsq;
    }

    // PV: A = P (rows q, k=m), B = V^T rows d
    bf16x8 pa[2], vf[4][2];
#pragma unroll
    for (int c = 0; c < 2; ++c)
      pa[c] = *(const bf16x8*)&pls[wave][lr][c * 32 + lg * 8];
#pragma unroll
    for (int dn = 0; dn < 4; ++dn)
#pragma unroll
      for (int c = 0; c < 2; ++c)
        vf[dn][c] = *(const bf16x8*)&vp[(size_t)(dn * 16 + lr) * 1024 + kb2 * 64 + c * 32 + lg * 8];
#pragma unroll
    for (int dn = 0; dn < 4; ++dn) {
      of[dn] = __builtin_amdgcn_mfma_f32_16x16x32_bf16(pa[0], vf[dn][0], of[dn], 0, 0, 0);
      of[dn] = __builtin_amdgcn_mfma_f32_16x16x32_bf16(pa[1], vf[dn][1], of[dn], 0, 0, 0);
    }
  }

  // epilogue: q = qw0 + lg*4 + r, d = dn*16 + lr
#pragma unroll
  for (int r = 0; r < 4; ++r) {
    float linv = 1.f / __shfl(lrow, (lane & 48) | (lg * 4 + r));
    int n = qw0 + lg * 4 + r;
#pragma unroll
    for (int dn = 0; dn < 4; ++dn) {
      int dd = dn * 16 + lr;
      merged[((size_t)(b * 1024 + n)) * 512 + h * 64 + dd] = (__bf16)(of[dn][r] * linv);
    }
  }
}

// ---------------- output projection GEMM: fp32 out + bias ----------------
__global__ __launch_bounds__(256) void out_gemm_kernel(const __bf16* __restrict__ A,
                                                       const __bf16* __restrict__ Bt,
                                                       const float* __restrict__ bo,
                                                       float* __restrict__ out) {
  int m0 = blockIdx.y * 128, n0 = blockIdx.x * 128;
  f32x4 acc[4][4];
  gemm_mainloop_128(A, Bt, 512, m0, n0, acc);
  int tid = threadIdx.x, wave = tid >> 6, lane = tid & 63;
  int wm = (wave >> 1) * 64, wn = (wave & 1) * 64, lg = lane >> 4, lr = lane & 15;
#pragma unroll
  for (int i = 0; i < 4; ++i)
#pragma unroll
    for (int j = 0; j < 4; ++j)
#pragma unroll
      for (int r = 0; r < 4; ++r) {
        int grow = m0 + wm + i * 16 + lg * 4 + r;
        int gcol = n0 + wn + j * 16 + lr;
        out[(size_t)grow * 512 + gcol] = acc[i][j][r] + bo[gcol];
      }
}

extern "C" void kernel_launch(void* const* d_in, const int* in_sizes, int n_in,
                              void* d_out, int out_size, void* d_ws, size_t ws_size,
                              hipStream_t stream) {
  const float* tokens = (const float*)d_in[0];
  const float* pf     = (const float*)d_in[1];
  const float* Wq     = (const float*)d_in[2];
  const float* bq     = (const float*)d_in[3];
  const float* Wk     = (const float*)d_in[4];
  const float* bk     = (const float*)d_in[5];
  const float* Wv     = (const float*)d_in[6];
  const float* bv     = (const float*)d_in[7];
  const float* Wo     = (const float*)d_in[8];
  const float* bo     = (const float*)d_in[9];
  const float* Wp     = (const float*)d_in[10];
  float* out = (float*)d_out;

  char* ws = (char*)d_ws;
  size_t off = 0;
  auto alloc = [&](size_t bytes) { char* p = ws + off; off += (bytes + 255) & ~(size_t)255; return p; };
  __bf16* tok_bf = (__bf16*)alloc((size_t)4096 * 512 * 2);
  __bf16* WcatT  = (__bf16*)alloc((size_t)1536 * 512 * 2);
  __bf16* WoT    = (__bf16*)alloc((size_t)512 * 512 * 2);
  __bf16* qb     = (__bf16*)alloc((size_t)32 * 1024 * 64 * 2);
  __bf16* kb     = (__bf16*)alloc((size_t)32 * 1024 * 64 * 2);
  __bf16* vtb    = (__bf16*)alloc((size_t)32 * 64 * 1024 * 2);
  __bf16* pbb    = (__bf16*)alloc((size_t)8 * 1024 * 1024 * 2);
  __bf16* merged = (__bf16*)alloc((size_t)4096 * 512 * 2);

  prep_kernel<<<PAIR_BLOCKS + CAST_BLOCKS + TR_BLOCKS, 256, 0, stream>>>(
      tokens, pf, Wq, Wk, Wv, Wo, Wp, tok_bf, WcatT, WoT, pbb);
  qkv_gemm_kernel<<<dim3(12, 32), 256, 0, stream>>>(tok_bf, WcatT, bq, bk, bv, qb, kb, vtb);
  flash_kernel<<<dim3(16, 32), 256, 0, stream>>>(qb, kb, vtb, pbb, merged);
  out_gemm_kernel<<<dim3(4, 32), 256, 0, stream>>>(merged, WoT, bo, out);
}